// Round 18
// baseline (235.065 us; speedup 1.0000x reference)
//
#include <hip/hip_runtime.h>
#include <math.h>

#define B_ 32768
#define D_ 512
#define E_ 64
#define H_ 5376
#define H4_ (H_ / 4)
#define HC_ 128            // floats per dispatch H-chunk
#define NCH_ (H_ / HC_)    // 42 chunks

typedef float f32x4 __attribute__((ext_vector_type(4)));
typedef _Float16 f16x8 __attribute__((ext_vector_type(8)));
typedef unsigned int u32x4 __attribute__((ext_vector_type(4)));

__device__ __forceinline__ unsigned short f16bits(_Float16 h) {
    union { _Float16 h; unsigned short u; } c; c.h = h; return c.u;
}

// ---- prep: W' = [wgate|wnoise]^T * 1024, two-term f16 split, [128 cols][512 k] ----
__global__ __launch_bounds__(256) void prep_kernel(
    const float* __restrict__ wgate, const float* __restrict__ wnoise,
    _Float16* __restrict__ wt0, _Float16* __restrict__ wt1)
{
    int e = blockIdx.x;                       // output column 0..127
    const float* src = (e < E_) ? (wgate + e) : (wnoise + (e - E_));
    for (int k = threadIdx.x; k < D_; k += 256) {
        float v = src[(size_t)k * E_] * 1024.0f;
        _Float16 h0 = (_Float16)v;
        _Float16 h1 = (_Float16)(v - (float)h0);
        wt0[(size_t)e * D_ + k] = h0;
        wt1[(size_t)e * D_ + k] = h1;
    }
}

// one top-5 extraction step, ALL STATIC indexing
#define TOP5_STEP(TV, TI)                                              \
    {                                                                  \
        double bm = v0; int bj = 0;                                    \
        if (v1 > bm) { bm = v1; bj = 1; }                              \
        if (v2 > bm) { bm = v2; bj = 2; }                              \
        if (v3 > bm) { bm = v3; bj = 3; }                              \
        int be = bj * 16 + le;                                         \
        _Pragma("unroll")                                              \
        for (int off = 1; off < 16; off <<= 1) {                       \
            double om = __shfl_xor(bm, off, 64);                       \
            int    oe = __shfl_xor(be, off, 64);                       \
            if (om > bm || (om == bm && oe < be)) { bm = om; be = oe; }\
        }                                                              \
        TV = bm; TI = be;                                              \
        bool wn = ((be & 15) == le); int sl = be >> 4;                 \
        v0 = (wn && sl == 0) ? -1.0e300 : v0;                          \
        v1 = (wn && sl == 1) ? -1.0e300 : v1;                          \
        v2 = (wn && sl == 2) ? -1.0e300 : v2;                          \
        v3 = (wn && sl == 3) ? -1.0e300 : v3;                          \
    }

// issue the 4 global float4-pair loads of K-quarter Q into ra[] (512 threads)
#define ISSUE_LOADS(Q)                                                         \
    _Pragma("unroll")                                                          \
    for (int i = 0; i < 2; ++i) {                                              \
        int id  = t + 512 * i;                                                 \
        const float* src = x + (size_t)(b0 + (id >> 4)) * D_ + (Q) * 128 +     \
                           (id & 15) * 8;                                      \
        ra[2 * i]     = *(const float4*)src;                                   \
        ra[2 * i + 1] = *(const float4*)(src + 4);                             \
    }

// convert ra[] (f16 two-term split) and write into LDS buffer BUF
#define CONVERT_WRITE(BUF)                                                     \
    _Pragma("unroll")                                                          \
    for (int i = 0; i < 2; ++i) {                                              \
        int id  = t + 512 * i;                                                 \
        int row = id >> 4;                                                     \
        int c   = id & 15;                                                     \
        float vv[8] = {ra[2*i].x, ra[2*i].y, ra[2*i].z, ra[2*i].w,             \
                       ra[2*i+1].x, ra[2*i+1].y, ra[2*i+1].z, ra[2*i+1].w};    \
        unsigned int hw[4], lw[4];                                             \
        _Pragma("unroll")                                                      \
        for (int p = 0; p < 4; ++p) {                                          \
            float va = vv[2*p] * 16.0f, vb = vv[2*p+1] * 16.0f;                \
            _Float16 a0 = (_Float16)va, b0f = (_Float16)vb;                    \
            _Float16 a1 = (_Float16)((va - (float)a0) * 4096.0f);              \
            _Float16 b1 = (_Float16)((vb - (float)b0f) * 4096.0f);             \
            hw[p] = (unsigned)f16bits(a0) | ((unsigned)f16bits(b0f) << 16);    \
            lw[p] = (unsigned)f16bits(a1) | ((unsigned)f16bits(b1) << 16);     \
        }                                                                      \
        int addr = (row * 256 + c * 16) ^ ((row & 7) << 4);                    \
        *(u32x4*)((char*)x0s[BUF] + addr) = (u32x4){hw[0], hw[1], hw[2], hw[3]};\
        *(u32x4*)((char*)x1s[BUF] + addr) = (u32x4){lw[0], lw[1], lw[2], lw[3]};\
    }

// ---- gate: 8-wave n-split. Waves 0-3 = gate experts (cols 0..63), waves 4-7 =
// noise (cols 64..127), same 64 rows. Doubles waves/CU (8->16) at same LDS.
// Noise waves hand sdf to clean waves via LDS (aliased onto retired x0s[0]).
__global__ __launch_bounds__(512) void gate_kernel(
    const float* __restrict__ x,
    const _Float16* __restrict__ wt0,
    const _Float16* __restrict__ wt1,
    const float* __restrict__ noise,
    unsigned int* __restrict__ o_idx,
    float4* __restrict__ o_g,
    float* __restrict__ g_imp,
    float* __restrict__ g_load)
{
    __shared__ __align__(16) _Float16 x0s[2][64 * 128];  // 2 x 16 KB (dbuf)
    __shared__ __align__(16) _Float16 x1s[2][64 * 128];  // 2 x 16 KB
    __shared__ float s_imp[E_];
    __shared__ float s_load[E_];
    float* sdn = (float*)x0s[0];   // [64 tok][64 e] f32 = 16 KB, alias (see barriers)

    const int t    = threadIdx.x;
    const int w    = t >> 6;       // wave 0..7
    const int half = w >> 2;       // 0 = gate cols, 1 = noise cols
    const int mt   = w & 3;        // row-tile 0..3
    const int l    = t & 63;
    const int le   = l & 15;
    const int g    = l >> 4;
    const int b0   = blockIdx.x * 64;
    const int arow = mt * 16 + le;
    const int nbase = half * 64;   // W' column offset

    if (t < E_) { s_imp[t] = 0.0f; s_load[t] = 0.0f; }

    f32x4 accAC[4], accB[4];
#pragma unroll
    for (int n = 0; n < 4; ++n) {
        accAC[n] = (f32x4){0.f, 0.f, 0.f, 0.f};
        accB[n]  = (f32x4){0.f, 0.f, 0.f, 0.f};
    }

    float4 ra[4];                  // in-flight staging (16 VGPR)
    ISSUE_LOADS(0)
    CONVERT_WRITE(0)

#pragma unroll
    for (int q = 0; q < 4; ++q) {
        if (q < 3) ISSUE_LOADS(q + 1)          // overlap HBM latency w/ MFMA
        __syncthreads();                       // buf[q&1] writes visible
#pragma unroll
        for (int s = 0; s < 4; ++s) {
            int aoff = (arow * 256 + s * 64 + g * 16) ^ ((arow & 7) << 4);
            f16x8 a0 = *(const f16x8*)((const char*)x0s[q & 1] + aoff);
            f16x8 a1 = *(const f16x8*)((const char*)x1s[q & 1] + aoff);
            int ks = q * 4 + s;
#pragma unroll
            for (int n = 0; n < 4; ++n) {
                size_t boff = (size_t)(nbase + n * 16 + le) * D_ + ks * 32 + g * 8;
                f16x8 b0 = *(const f16x8*)(wt0 + boff);
                f16x8 b1 = *(const f16x8*)(wt1 + boff);
                accAC[n] = __builtin_amdgcn_mfma_f32_16x16x32_f16(a0, b0, accAC[n], 0, 0, 0);
                accAC[n] = __builtin_amdgcn_mfma_f32_16x16x32_f16(a0, b1, accAC[n], 0, 0, 0);
                accB[n]  = __builtin_amdgcn_mfma_f32_16x16x32_f16(a1, b0, accB[n],  0, 0, 0);
            }
        }
        if (q < 3) CONVERT_WRITE((q + 1) & 1)  // writes other buffer: no race
    }

    const double UNSCALE = 1.0 / 16384.0;
    const double RESC    = 1.0 / 4096.0;

    __syncthreads();               // all q=3 reads of x0s done -> sdn alias safe
    if (half == 1) {
        // noise waves: sdf = softplus(z)+0.01 (identical f32 math to R15)
#pragma unroll
        for (int r = 0; r < 4; ++r) {
            int li = mt * 16 + g * 4 + r;
#pragma unroll
            for (int n = 0; n < 4; ++n) {
                float z = (float)(((double)accAC[n][r] + (double)accB[n][r] * RESC) * UNSCALE);
                float sp = (z > 20.0f) ? z : log1pf(expf(z));
                sdn[li * 64 + 16 * n + le] = sp + 0.01f;
            }
        }
    }
    __syncthreads();               // sdf visible to clean waves

    if (half == 0) {
        float loadacc[4] = {0.f, 0.f, 0.f, 0.f};
#pragma unroll
        for (int r = 0; r < 4; ++r) {
            int li = mt * 16 + g * 4 + r;
            int b  = b0 + li;
            double cl[4], ny[4];
            float  sdf[4];
#pragma unroll
            for (int n = 0; n < 4; ++n) {
                cl[n] = ((double)accAC[n][r] + (double)accB[n][r] * RESC) * UNSCALE;
                sdf[n] = sdn[li * 64 + 16 * n + le];
                float nz = noise[(size_t)b * E_ + le + 16 * n];
                ny[n] = cl[n] + (double)(nz * sdf[n]);
            }
            double v0 = ny[0], v1 = ny[1], v2 = ny[2], v3 = ny[3];
            double tv0, tv1, tv2, tv3, tv4;
            int    ti0, ti1, ti2, ti3, ti4;
            TOP5_STEP(tv0, ti0)
            TOP5_STEP(tv1, ti1)
            TOP5_STEP(tv2, ti2)
            TOP5_STEP(tv3, ti3)
            TOP5_STEP(tv4, ti4)
            float e1 = expf((float)(tv1 - tv0)),
                  e2 = expf((float)(tv2 - tv0)),
                  e3 = expf((float)(tv3 - tv0));
            float inv = 1.0f / (1.0f + e1 + e2 + e3);
            float g0 = inv, g1 = e1 * inv, g2 = e2 * inv, g3 = e3 * inv;
            if (le == 0) {
                o_idx[b] = (unsigned)ti0 | ((unsigned)ti1 << 8) |
                           ((unsigned)ti2 << 16) | ((unsigned)ti3 << 24);
                float4 gv; gv.x = g0; gv.y = g1; gv.z = g2; gv.w = g3;
                o_g[b] = gv;
                atomicAdd(&s_imp[ti0], g0);
                atomicAdd(&s_imp[ti1], g1);
                atomicAdd(&s_imp[ti2], g2);
                atomicAdd(&s_imp[ti3], g3);
            }
            double thr_out = tv3;   // 4th largest
            double thr_in  = tv4;   // 5th largest
#pragma unroll
            for (int n = 0; n < 4; ++n) {
                double thr = (ny[n] > thr_in) ? thr_in : thr_out;
                float  zz  = (float)(cl[n] - thr) / sdf[n];
                loadacc[n] += 0.5f * (1.0f + erff(zz * 0.70710678118654752f));
            }
        }
#pragma unroll
        for (int n = 0; n < 4; ++n) atomicAdd(&s_load[16 * n + le], loadacc[n]);
    }
    __syncthreads();
    if (t < E_) {
        atomicAdd(&g_imp[t],  s_imp[t]);
        atomicAdd(&g_load[t], s_load[t]);
    }
}

// ---- dispatch: LDS-staged tiling (R9 config, at write floor ~117 us) ----
__global__ __launch_bounds__(256) void dispatch_kernel(
    const float* __restrict__ ctx,
    const unsigned int* __restrict__ o_idx,
    const float4* __restrict__ o_g,
    float* __restrict__ out)
{
    __shared__ f32x4 cs[E_ * (HC_ / 4)];   // [64 experts][32 float4] = 32 KB

    const int t  = threadIdx.x;
    const int h0 = blockIdx.x * HC_;
    const int tb = blockIdx.y * 64;

#pragma unroll
    for (int i = 0; i < 8; ++i) {
        int idx = t + 256 * i;
        int e = idx >> 5, c = idx & 31;
        cs[idx] = *(const f32x4*)&ctx[(size_t)e * H_ + h0 + c * 4];
    }
    __syncthreads();

    const int tok = t >> 5;
    const int c   = t & 31;
#pragma unroll
    for (int s = 0; s < 8; ++s) {
        int b = tb + s * 8 + tok;
        unsigned pk = o_idx[b];
        float4 g = o_g[b];
        f32x4 r = g.x * cs[((pk      ) & 255u) * 32 + c]
                + g.y * cs[((pk >>  8) & 255u) * 32 + c]
                + g.z * cs[((pk >> 16) & 255u) * 32 + c]
                + g.w * cs[( pk >> 24         ) * 32 + c];
        __builtin_nontemporal_store(r, (f32x4*)&out[(size_t)b * H_ + h0 + c * 4]);
    }
}

__global__ void loss_kernel(const float* __restrict__ g_imp,
                            const float* __restrict__ g_load,
                            float* __restrict__ out)
{
    int e = threadIdx.x;   // 64 threads
    double vi = (double)g_imp[e];
    double vl = (double)g_load[e];
    double si = vi, sl = vl;
#pragma unroll
    for (int off = 1; off < 64; off <<= 1) {
        si += __shfl_xor(si, off, 64);
        sl += __shfl_xor(sl, off, 64);
    }
    double mi = si / 64.0, ml = sl / 64.0;
    double di = vi - mi, dl = vl - ml;
    double qi = di * di, ql = dl * dl;
#pragma unroll
    for (int off = 1; off < 64; off <<= 1) {
        qi += __shfl_xor(qi, off, 64);
        ql += __shfl_xor(ql, off, 64);
    }
    double vari = qi / 64.0, varl = ql / 64.0;
    double cv2i = vari / (mi * mi + 1e-10);
    double cv2l = varl / (ml * ml + 1e-10);
    if (e == 0) out[(size_t)B_ * H_] = (float)((cv2i + cv2l) * 0.01);
}

extern "C" void kernel_launch(void* const* d_in, const int* in_sizes, int n_in,
                              void* d_out, int out_size, void* d_ws, size_t ws_size,
                              hipStream_t stream)
{
    const float* x      = (const float*)d_in[0];
    const float* wgate  = (const float*)d_in[1];
    const float* wnoise = (const float*)d_in[2];
    const float* noise  = (const float*)d_in[3];
    const float* ctx    = (const float*)d_in[4];
    float* out    = (float*)d_out;
    float* g_imp  = (float*)d_ws;                     // 64 f32
    float* g_load = g_imp + E_;                       // 64 f32
    _Float16* wt0 = (_Float16*)(g_load + E_);         // 128*512 f16
    _Float16* wt1 = wt0 + 128 * D_;                   // 128*512 f16
    unsigned int* o_idx = (unsigned int*)(wt1 + 128 * D_);  // 32768 u32
    float4* o_g = (float4*)(o_idx + B_);                    // 32768 float4

    (void)hipMemsetAsync(d_ws, 0, 2 * E_ * sizeof(float), stream);
    prep_kernel<<<128, 256, 0, stream>>>(wgate, wnoise, wt0, wt1);
    gate_kernel<<<B_ / 64, 512, 0, stream>>>(x, wt0, wt1, noise,
                                             o_idx, o_g, g_imp, g_load);
    dispatch_kernel<<<dim3(NCH_, B_ / 64), 256, 0, stream>>>(ctx, o_idx, o_g, out);
    loss_kernel<<<1, 64, 0, stream>>>(g_imp, g_load, out);
}

// Round 19
// 197.859 us; speedup vs baseline: 1.1880x; 1.1880x over previous
//
#include <hip/hip_runtime.h>
#include <math.h>

#define B_ 32768
#define D_ 512
#define E_ 64
#define H_ 5376
#define H4_ (H_ / 4)
#define HC_ 128            // floats per dispatch H-chunk
#define NCH_ (H_ / HC_)    // 42 chunks

typedef float f32x4 __attribute__((ext_vector_type(4)));
typedef _Float16 f16x8 __attribute__((ext_vector_type(8)));
typedef unsigned int u32x4 __attribute__((ext_vector_type(4)));

__device__ __forceinline__ unsigned short f16bits(_Float16 h) {
    union { _Float16 h; unsigned short u; } c; c.h = h; return c.u;
}

// ---- prep: W' = [wgate|wnoise]^T * 1024, two-term f16 split ----
// FRAGMENT-CONTIGUOUS layout: element (col,k) with n=col>>4, le=col&15,
// ks=k>>5, g=(k&31)>>3, j=k&7 goes to ((ks*8+n)*64 + g*16+le)*8 + j.
// A wave's B-fragment load for (ks,n) is then 64 lanes x 16B CONTIGUOUS (1KB).
__global__ __launch_bounds__(256) void prep_kernel(
    const float* __restrict__ wgate, const float* __restrict__ wnoise,
    _Float16* __restrict__ wt0, _Float16* __restrict__ wt1)
{
    int e = blockIdx.x;                       // output column 0..127
    int n  = e >> 4, le = e & 15;
    const float* src = (e < E_) ? (wgate + e) : (wnoise + (e - E_));
    for (int k = threadIdx.x; k < D_; k += 256) {
        float v = src[(size_t)k * E_] * 1024.0f;
        _Float16 h0 = (_Float16)v;
        _Float16 h1 = (_Float16)(v - (float)h0);
        int ks = k >> 5, g = (k & 31) >> 3, j = k & 7;
        size_t idx = ((size_t)(ks * 8 + n) * 64 + g * 16 + le) * 8 + j;
        wt0[idx] = h0;
        wt1[idx] = h1;
    }
}

// one top-5 extraction step, ALL STATIC indexing
#define TOP5_STEP(TV, TI)                                              \
    {                                                                  \
        double bm = v0; int bj = 0;                                    \
        if (v1 > bm) { bm = v1; bj = 1; }                              \
        if (v2 > bm) { bm = v2; bj = 2; }                              \
        if (v3 > bm) { bm = v3; bj = 3; }                              \
        int be = bj * 16 + le;                                         \
        _Pragma("unroll")                                              \
        for (int off = 1; off < 16; off <<= 1) {                       \
            double om = __shfl_xor(bm, off, 64);                       \
            int    oe = __shfl_xor(be, off, 64);                       \
            if (om > bm || (om == bm && oe < be)) { bm = om; be = oe; }\
        }                                                              \
        TV = bm; TI = be;                                              \
        bool wn = ((be & 15) == le); int sl = be >> 4;                 \
        v0 = (wn && sl == 0) ? -1.0e300 : v0;                          \
        v1 = (wn && sl == 1) ? -1.0e300 : v1;                          \
        v2 = (wn && sl == 2) ? -1.0e300 : v2;                          \
        v3 = (wn && sl == 3) ? -1.0e300 : v3;                          \
    }

// issue the 8 global float4 loads of K-quarter Q into ra[]
#define ISSUE_LOADS(Q)                                                         \
    _Pragma("unroll")                                                          \
    for (int i = 0; i < 4; ++i) {                                              \
        int id  = t + 256 * i;                                                 \
        const float* src = x + (size_t)(b0 + (id >> 4)) * D_ + (Q) * 128 +     \
                           (id & 15) * 8;                                      \
        ra[2 * i]     = *(const float4*)src;                                   \
        ra[2 * i + 1] = *(const float4*)(src + 4);                             \
    }

// convert ra[] (f16 two-term split) and write into LDS buffer BUF
#define CONVERT_WRITE(BUF)                                                     \
    _Pragma("unroll")                                                          \
    for (int i = 0; i < 4; ++i) {                                              \
        int id  = t + 256 * i;                                                 \
        int row = id >> 4;                                                     \
        int c   = id & 15;                                                     \
        float vv[8] = {ra[2*i].x, ra[2*i].y, ra[2*i].z, ra[2*i].w,             \
                       ra[2*i+1].x, ra[2*i+1].y, ra[2*i+1].z, ra[2*i+1].w};    \
        unsigned int hw[4], lw[4];                                             \
        _Pragma("unroll")                                                      \
        for (int p = 0; p < 4; ++p) {                                          \
            float va = vv[2*p] * 16.0f, vb = vv[2*p+1] * 16.0f;                \
            _Float16 a0 = (_Float16)va, b0f = (_Float16)vb;                    \
            _Float16 a1 = (_Float16)((va - (float)a0) * 4096.0f);              \
            _Float16 b1 = (_Float16)((vb - (float)b0f) * 4096.0f);             \
            hw[p] = (unsigned)f16bits(a0) | ((unsigned)f16bits(b0f) << 16);    \
            lw[p] = (unsigned)f16bits(a1) | ((unsigned)f16bits(b1) << 16);     \
        }                                                                      \
        int addr = (row * 256 + c * 16) ^ ((row & 7) << 4);                    \
        *(u32x4*)((char*)x0s[BUF] + addr) = (u32x4){hw[0], hw[1], hw[2], hw[3]};\
        *(u32x4*)((char*)x1s[BUF] + addr) = (u32x4){lw[0], lw[1], lw[2], lw[3]};\
    }

// ---- gate: f16 split-MFMA GEMM, pipelined staging + fragment-contiguous W ----
// accAC = x0*(w0+w1) (scale 2^14); accB = x1*w0 (scale 2^26);
// logit = (accAC + accB/4096)/16384.  n=0..3 gate, n=4..7 noise experts 16n+le.
__global__ __launch_bounds__(256) void gate_kernel(
    const float* __restrict__ x,
    const _Float16* __restrict__ wt0,
    const _Float16* __restrict__ wt1,
    const float* __restrict__ noise,
    unsigned int* __restrict__ o_idx,
    float4* __restrict__ o_g,
    float* __restrict__ g_imp,
    float* __restrict__ g_load)
{
    __shared__ __align__(16) _Float16 x0s[2][64 * 128];  // 2 x 16 KB (dbuf)
    __shared__ __align__(16) _Float16 x1s[2][64 * 128];  // 2 x 16 KB
    __shared__ float s_imp[E_];
    __shared__ float s_load[E_];

    const int t  = threadIdx.x;
    const int w  = t >> 6;        // wave 0..3
    const int l  = t & 63;        // lane
    const int le = l & 15;
    const int g  = l >> 4;
    const int b0 = blockIdx.x * 64;
    const int arow = w * 16 + le;

    if (t < E_) { s_imp[t] = 0.0f; s_load[t] = 0.0f; }

    f32x4 accAC[8], accB[8];
#pragma unroll
    for (int n = 0; n < 8; ++n) {
        accAC[n] = (f32x4){0.f, 0.f, 0.f, 0.f};
        accB[n]  = (f32x4){0.f, 0.f, 0.f, 0.f};
    }

    float4 ra[8];                 // in-flight staging quarter (32 VGPR)
    ISSUE_LOADS(0)
    CONVERT_WRITE(0)

#pragma unroll
    for (int q = 0; q < 4; ++q) {
        if (q < 3) ISSUE_LOADS(q + 1)          // overlap HBM latency w/ MFMA
        __syncthreads();                       // buf[q&1] writes visible
#pragma unroll
        for (int s = 0; s < 4; ++s) {
            int aoff = (arow * 256 + s * 64 + g * 16) ^ ((arow & 7) << 4);
            f16x8 a0 = *(const f16x8*)((const char*)x0s[q & 1] + aoff);
            f16x8 a1 = *(const f16x8*)((const char*)x1s[q & 1] + aoff);
            int ks = q * 4 + s;
#pragma unroll
            for (int n = 0; n < 8; ++n) {
                size_t boff = ((size_t)(ks * 8 + n) * 64 + l) * 8;  // 1KB-contig/wave
                f16x8 b0 = *(const f16x8*)(wt0 + boff);
                f16x8 b1 = *(const f16x8*)(wt1 + boff);
                accAC[n] = __builtin_amdgcn_mfma_f32_16x16x32_f16(a0, b0, accAC[n], 0, 0, 0);
                accAC[n] = __builtin_amdgcn_mfma_f32_16x16x32_f16(a0, b1, accAC[n], 0, 0, 0);
                accB[n]  = __builtin_amdgcn_mfma_f32_16x16x32_f16(a1, b0, accB[n],  0, 0, 0);
            }
        }
        if (q < 3) CONVERT_WRITE((q + 1) & 1)  // writes other buffer: no race
    }

    // ---- epilogue: float transcendentals, f64 values/compares (R15) ----
    const double UNSCALE = 1.0 / 16384.0;
    const double RESC    = 1.0 / 4096.0;
    float loadacc[4] = {0.f, 0.f, 0.f, 0.f};
#pragma unroll
    for (int r = 0; r < 4; ++r) {
        int li = w * 16 + g * 4 + r;   // local token (C row)
        int b  = b0 + li;
        double cl[4], ny[4];
        float  sdf[4];
#pragma unroll
        for (int n = 0; n < 4; ++n) {
            cl[n] = ((double)accAC[n][r] + (double)accB[n][r] * RESC) * UNSCALE;
            float z = (float)(((double)accAC[n+4][r] + (double)accB[n+4][r] * RESC) * UNSCALE);
            float sp = (z > 20.0f) ? z : log1pf(expf(z));
            sdf[n] = sp + 0.01f;
            float nz = noise[(size_t)b * E_ + le + 16 * n];
            ny[n] = cl[n] + (double)(nz * sdf[n]);
        }
        double v0 = ny[0], v1 = ny[1], v2 = ny[2], v3 = ny[3];
        double tv0, tv1, tv2, tv3, tv4;
        int    ti0, ti1, ti2, ti3, ti4;
        TOP5_STEP(tv0, ti0)
        TOP5_STEP(tv1, ti1)
        TOP5_STEP(tv2, ti2)
        TOP5_STEP(tv3, ti3)
        TOP5_STEP(tv4, ti4)
        float e1 = expf((float)(tv1 - tv0)),
              e2 = expf((float)(tv2 - tv0)),
              e3 = expf((float)(tv3 - tv0));
        float inv = 1.0f / (1.0f + e1 + e2 + e3);
        float g0 = inv, g1 = e1 * inv, g2 = e2 * inv, g3 = e3 * inv;
        if (le == 0) {
            o_idx[b] = (unsigned)ti0 | ((unsigned)ti1 << 8) |
                       ((unsigned)ti2 << 16) | ((unsigned)ti3 << 24);
            float4 gv; gv.x = g0; gv.y = g1; gv.z = g2; gv.w = g3;
            o_g[b] = gv;
            atomicAdd(&s_imp[ti0], g0);
            atomicAdd(&s_imp[ti1], g1);
            atomicAdd(&s_imp[ti2], g2);
            atomicAdd(&s_imp[ti3], g3);
        }
        double thr_out = tv3;   // 4th largest
        double thr_in  = tv4;   // 5th largest
#pragma unroll
        for (int n = 0; n < 4; ++n) {
            double thr = (ny[n] > thr_in) ? thr_in : thr_out;
            float  zz  = (float)(cl[n] - thr) / sdf[n];
            loadacc[n] += 0.5f * (1.0f + erff(zz * 0.70710678118654752f));
        }
    }
#pragma unroll
    for (int n = 0; n < 4; ++n) atomicAdd(&s_load[16 * n + le], loadacc[n]);
    __syncthreads();
    if (t < E_) {
        atomicAdd(&g_imp[t],  s_imp[t]);
        atomicAdd(&g_load[t], s_load[t]);
    }
}

// ---- dispatch: LDS-staged tiling (R9 config, at write floor ~117 us) ----
__global__ __launch_bounds__(256) void dispatch_kernel(
    const float* __restrict__ ctx,
    const unsigned int* __restrict__ o_idx,
    const float4* __restrict__ o_g,
    float* __restrict__ out)
{
    __shared__ f32x4 cs[E_ * (HC_ / 4)];   // [64 experts][32 float4] = 32 KB

    const int t  = threadIdx.x;
    const int h0 = blockIdx.x * HC_;
    const int tb = blockIdx.y * 64;

#pragma unroll
    for (int i = 0; i < 8; ++i) {
        int idx = t + 256 * i;
        int e = idx >> 5, c = idx & 31;
        cs[idx] = *(const f32x4*)&ctx[(size_t)e * H_ + h0 + c * 4];
    }
    __syncthreads();

    const int tok = t >> 5;
    const int c   = t & 31;
#pragma unroll
    for (int s = 0; s < 8; ++s) {
        int b = tb + s * 8 + tok;
        unsigned pk = o_idx[b];
        float4 g = o_g[b];
        f32x4 r = g.x * cs[((pk      ) & 255u) * 32 + c]
                + g.y * cs[((pk >>  8) & 255u) * 32 + c]
                + g.z * cs[((pk >> 16) & 255u) * 32 + c]
                + g.w * cs[( pk >> 24         ) * 32 + c];
        __builtin_nontemporal_store(r, (f32x4*)&out[(size_t)b * H_ + h0 + c * 4]);
    }
}

__global__ void loss_kernel(const float* __restrict__ g_imp,
                            const float* __restrict__ g_load,
                            float* __restrict__ out)
{
    int e = threadIdx.x;   // 64 threads
    double vi = (double)g_imp[e];
    double vl = (double)g_load[e];
    double si = vi, sl = vl;
#pragma unroll
    for (int off = 1; off < 64; off <<= 1) {
        si += __shfl_xor(si, off, 64);
        sl += __shfl_xor(sl, off, 64);
    }
    double mi = si / 64.0, ml = sl / 64.0;
    double di = vi - mi, dl = vl - ml;
    double qi = di * di, ql = dl * dl;
#pragma unroll
    for (int off = 1; off < 64; off <<= 1) {
        qi += __shfl_xor(qi, off, 64);
        ql += __shfl_xor(ql, off, 64);
    }
    double vari = qi / 64.0, varl = ql / 64.0;
    double cv2i = vari / (mi * mi + 1e-10);
    double cv2l = varl / (ml * ml + 1e-10);
    if (e == 0) out[(size_t)B_ * H_] = (float)((cv2i + cv2l) * 0.01);
}

extern "C" void kernel_launch(void* const* d_in, const int* in_sizes, int n_in,
                              void* d_out, int out_size, void* d_ws, size_t ws_size,
                              hipStream_t stream)
{
    const float* x      = (const float*)d_in[0];
    const float* wgate  = (const float*)d_in[1];
    const float* wnoise = (const float*)d_in[2];
    const float* noise  = (const float*)d_in[3];
    const float* ctx    = (const float*)d_in[4];
    float* out    = (float*)d_out;
    float* g_imp  = (float*)d_ws;                     // 64 f32
    float* g_load = g_imp + E_;                       // 64 f32
    _Float16* wt0 = (_Float16*)(g_load + E_);         // 128*512 f16 (frag-contig)
    _Float16* wt1 = wt0 + 128 * D_;                   // 128*512 f16
    unsigned int* o_idx = (unsigned int*)(wt1 + 128 * D_);  // 32768 u32
    float4* o_g = (float4*)(o_idx + B_);                    // 32768 float4

    (void)hipMemsetAsync(d_ws, 0, 2 * E_ * sizeof(float), stream);
    prep_kernel<<<128, 256, 0, stream>>>(wgate, wnoise, wt0, wt1);
    gate_kernel<<<B_ / 64, 256, 0, stream>>>(x, wt0, wt1, noise,
                                             o_idx, o_g, g_imp, g_load);
    dispatch_kernel<<<dim3(NCH_, B_ / 64), 256, 0, stream>>>(ctx, o_idx, o_g, out);
    loss_kernel<<<1, 64, 0, stream>>>(g_imp, g_load, out);
}